// Round 1
// baseline (143.348 us; speedup 1.0000x reference)
//
#include <hip/hip_runtime.h>
#include <hip/hip_bf16.h>
#include <stdint.h>

// TypedLinear: out[i] = W[types[i]] @ x[i] + b[types[i]]
// N=65536, IN=OUT=256, T=8, fp32 in/out. bf16-MFMA grouped-GEMM via type bucketing.

#define NROWS 65536
#define NTYPES 8
#define KDIM 256
#define ODIM 256
#define BM 128
#define BN 128
#define BK 64

typedef __attribute__((ext_vector_type(8))) short short8;
typedef __attribute__((ext_vector_type(4))) float f32x4;

__device__ __forceinline__ unsigned short f2bf(float f) {
    // round-to-nearest-even fp32 -> bf16
    unsigned int u = __float_as_uint(f);
    u += 0x7fffu + ((u >> 16) & 1u);
    return (unsigned short)(u >> 16);
}

// ---------------- prep: zero counters + W fp32 -> bf16 ----------------
// grid 512 x 256 threads, one float4 per thread (8*256*256/4 = 131072)
__global__ void prep_kernel(const float* __restrict__ W,
                            unsigned short* __restrict__ Wb,
                            int* __restrict__ cnt) {
    if (blockIdx.x == 0 && threadIdx.x < NTYPES) cnt[threadIdx.x] = 0;
    int i = blockIdx.x * 256 + threadIdx.x;
    float4 v = ((const float4*)W)[i];
    ushort4 p;
    p.x = f2bf(v.x); p.y = f2bf(v.y); p.z = f2bf(v.z); p.w = f2bf(v.w);
    ((ushort4*)Wb)[i] = p;
}

// ---------------- bucket: per-type index lists ----------------
// 256 blocks x 256 threads. LDS histogram -> 8 global atomics/block.
__global__ void bucket_kernel(const int* __restrict__ types,
                              int* __restrict__ cnt,
                              int* __restrict__ idx) {
    __shared__ int h[NTYPES];
    __shared__ int base[NTYPES];
    int i = blockIdx.x * 256 + threadIdx.x;
    if (threadIdx.x < NTYPES) h[threadIdx.x] = 0;
    __syncthreads();
    int t = types[i];
    int r = atomicAdd(&h[t], 1);
    __syncthreads();
    if (threadIdx.x < NTYPES)
        base[threadIdx.x] = atomicAdd(&cnt[threadIdx.x], h[threadIdx.x]);
    __syncthreads();
    idx[t * NROWS + base[t] + r] = i;
}

// ---------------- grouped GEMM ----------------
// grid (512, 2, 8) = (m-tile, n-tile, type); 256 threads = 4 waves (2x2 of 64x64).
// As/Bs are [128 rows][64 bf16] with 16B-chunk XOR swizzle: chunk' = chunk ^ (row&7).
__global__ __launch_bounds__(256, 2)
void gemm_kernel(const float* __restrict__ x,
                 const float* __restrict__ bias,
                 const unsigned short* __restrict__ Wb,
                 const int* __restrict__ cnt,
                 const int* __restrict__ idx,
                 float* __restrict__ out) {
    const int t = blockIdx.z;
    const int count = cnt[t];
    const int m0 = blockIdx.x * BM;
    if (m0 >= count) return;          // uniform early exit, before any barrier
    const int n0 = blockIdx.y * BN;

    __shared__ int idx_s[BM];
    __shared__ float bias_s[BN];
    __shared__ unsigned short As[BM * BK];   // 16 KB, swizzled
    __shared__ unsigned short Bs[BN * BK];   // 16 KB, swizzled

    const int tid = threadIdx.x;

    if (tid < BM) {
        int m = m0 + tid;
        idx_s[tid] = (m < count) ? idx[t * NROWS + m] : 0;
    } else {
        bias_s[tid - BM] = bias[t * ODIM + n0 + (tid - BM)];
    }
    __syncthreads();

    const int wave = tid >> 6;
    const int lane = tid & 63;
    const int lr = lane & 15;   // A-row / B-row / D-col within 16
    const int lq = lane >> 4;   // quad
    const int wm = (wave >> 1) * 64;
    const int wn = (wave & 1) * 64;

    f32x4 acc[4][4] = {};

    // A staging mapping: 16 threads per row, float4 each; 16 rows per sub-iter
    const int srow = tid >> 4;       // 0..15
    const int sc   = tid & 15;       // float4 slot within the 64-float row chunk

    char* AsB = (char*)As;
    char* BsB = (char*)Bs;

    for (int k0 = 0; k0 < KDIM; k0 += BK) {
        // ---- stage A: gather 128 rows x 64 fp32 -> bf16, swizzled
        #pragma unroll
        for (int j = 0; j < 8; ++j) {
            int row = j * 16 + srow;
            const float4 v = *(const float4*)(x + (size_t)idx_s[row] * KDIM + k0 + sc * 4);
            ushort4 p;
            p.x = f2bf(v.x); p.y = f2bf(v.y); p.z = f2bf(v.z); p.w = f2bf(v.w);
            int ch = (sc >> 1) ^ (row & 7);
            *(ushort4*)(AsB + row * 128 + ch * 16 + (sc & 1) * 8) = p;
        }
        // ---- stage B: global_load_lds 16B/lane from preconverted bf16 W.
        // dest = wave-uniform base + lane*16; swizzle applied on the SOURCE address.
        #pragma unroll
        for (int it = 0; it < 4; ++it) {
            int dbyte = wave * 4096 + it * 1024;           // wave-uniform LDS base
            int drow  = (dbyte >> 7) + (lane >> 3);        // row this lane fills
            int schunk = (lane & 7) ^ (lane >> 3);         // (chunk) ^ (row & 7)
            const unsigned short* src =
                Wb + (size_t)(t * ODIM + n0 + drow) * KDIM + k0 + schunk * 8;
            __builtin_amdgcn_global_load_lds(
                (const __attribute__((address_space(1))) void*)src,
                (__attribute__((address_space(3))) void*)(BsB + dbyte),
                16, 0, 0);
        }
        __syncthreads();

        // ---- compute: 2 x (4 A-frags, 4 B-frags, 16 MFMAs)
        #pragma unroll
        for (int kh = 0; kh < 2; ++kh) {      // k-half: chunk base 0 or 4
            short8 af[4], bf[4];
            #pragma unroll
            for (int i = 0; i < 4; ++i) {
                int arow = wm + i * 16 + lr;
                int ach = ((kh << 2) + lq) ^ (arow & 7);
                af[i] = *(const short8*)(AsB + arow * 128 + ach * 16);
            }
            #pragma unroll
            for (int i = 0; i < 4; ++i) {
                int brow = wn + i * 16 + lr;
                int bch = ((kh << 2) + lq) ^ (brow & 7);
                bf[i] = *(const short8*)(BsB + brow * 128 + bch * 16);
            }
            #pragma unroll
            for (int i = 0; i < 4; ++i)
                #pragma unroll
                for (int j = 0; j < 4; ++j)
                    acc[i][j] = __builtin_amdgcn_mfma_f32_16x16x32_bf16(
                        af[i], bf[j], acc[i][j], 0, 0, 0);
        }
        __syncthreads();
    }

    // ---- epilogue: D col = lane&15, row = (lane>>4)*4 + reg
    #pragma unroll
    for (int i = 0; i < 4; ++i) {
        int lmBase = wm + i * 16 + lq * 4;
        #pragma unroll
        for (int r = 0; r < 4; ++r) {
            int lm = lmBase + r;
            if (m0 + lm < count) {
                size_t orow = (size_t)idx_s[lm] * ODIM;
                #pragma unroll
                for (int j = 0; j < 4; ++j) {
                    int col = wn + j * 16 + lr;
                    out[orow + n0 + col] = acc[i][j][r] + bias_s[col];
                }
            }
        }
    }
}

extern "C" void kernel_launch(void* const* d_in, const int* in_sizes, int n_in,
                              void* d_out, int out_size, void* d_ws, size_t ws_size,
                              hipStream_t stream) {
    const float* x     = (const float*)d_in[0];
    const int*   types = (const int*)d_in[1];
    const float* W     = (const float*)d_in[2];
    const float* b     = (const float*)d_in[3];
    float* out = (float*)d_out;

    // ws layout: [0,32) cnt | [1024, 1024+2MB) idx | then 1MB bf16 W  (~3.1 MB total)
    char* ws = (char*)d_ws;
    int* cnt = (int*)ws;
    int* idx = (int*)(ws + 1024);
    unsigned short* Wb = (unsigned short*)(ws + 1024 + (size_t)NTYPES * NROWS * sizeof(int));

    prep_kernel<<<512, 256, 0, stream>>>(W, Wb, cnt);
    bucket_kernel<<<NROWS / 256, 256, 0, stream>>>(types, cnt, idx);
    dim3 grid(NROWS / BM, ODIM / BN, NTYPES);
    gemm_kernel<<<grid, 256, 0, stream>>>(x, b, Wb, cnt, idx, out);
}